// Round 1
// baseline (63.746 us; speedup 1.0000x reference)
//
#include <hip/hip_runtime.h>

#define Cc 384
#define Hh 56
#define Ww 56
#define PLANE (Hh*Ww)        // 3136 floats
#define NF4 14               // float4s per row

typedef short short8 __attribute__((ext_vector_type(8)));
typedef float f32x4  __attribute__((ext_vector_type(4)));
typedef unsigned int u32;
typedef u32 u32x4 __attribute__((ext_vector_type(4)));
struct __align__(16) f4 { float x, y, z, w; };

__device__ __forceinline__ u32 cvtpk_bf16(float a, float b) {
    u32 d; asm("v_cvt_pk_bf16_f32 %0, %1, %2" : "=v"(d) : "v"(a), "v"(b));
    return d;   // lo=bf16(a), hi=bf16(b), RNE
}
// 16B-block swizzle within a 256B Xt row: good for BOTH the staging scatter
// (w = 4*w4+q, w4 varies per lane) and the b128 frag reads (w = 16wv+l15):
// each lands <=2-way per 16-lane phase.
__device__ __forceinline__ int swz(int w) { return (w ^ (w >> 2)) & 7; }

// out = A(56x56 circulant) * X(56x56) per plane, padded to 64^3, bf16 MFMA.
// R13: occupancy 38->53->75% made dur WORSE -> not latency-bound.
// R14: both HBM streams fully contiguous (1KB/wave-instr) -> 57.5us.
// R15 (this round): DS pipe was co-critical with HBM (~2380 vs ~2500 cyc/blk).
//   Transposed decomposition: D = out^T = Xt * Wcirc^T.
//   A-operand = Xt rows (wave reads ONLY its 16 rows: 4KB, no 4x redundancy),
//   B-operand = Bt[h][m] = wt[(m-h)%56] bf16 table (8KB, b128 reads).
//   D written as ds_write_b128 (4/lane) instead of 16x ds_write_b32.
//   Phases 1/3 (contiguous HBM streams, Xt scatter, Cb->linear stores) unchanged.
// waves_per_eu(4,4): the only codegen mode without the VGPR-24 pathology.
__global__ __launch_bounds__(256) __attribute__((amdgpu_waves_per_eu(4, 4)))
void parc_kernel(const float* __restrict__ x, const float* __restrict__ pe,
                 const float* __restrict__ wgt, const float* __restrict__ bias,
                 float* __restrict__ out)
{
    __shared__ __align__(16) float Xt[64 * 64];            // [w][m] fp32, swizzled 16B blocks (16KB)
    __shared__ __align__(16) float Cb[56 * 60];            // [h][w] stride 60 dwords (13.4KB)
    __shared__ __align__(16) unsigned short Bt[64 * 72];   // [h][m] bf16, stride 72 (144B: 2-way banks on b128)

    const int t  = threadIdx.x;
    const int bc = blockIdx.x;          // plane index b*C + c
    const int c  = bc % Cc;

    const float* __restrict__ wc  = wgt + c * Hh;
    const float* __restrict__ pec = pe  + c * Hh;
    const f4* __restrict__ xin = reinterpret_cast<const f4*>(x) + (size_t)bc * (PLANE / 4);

    // ---- staging loads: linear f4 => 64 lanes x 16B = 1KB contiguous/instr ----
    f4 v0 = xin[t], v1 = xin[t + 256], v2 = xin[t + 512];
    const int r0 = t / NF4, r1 = (t + 256) / NF4, r2 = (t + 512) / NF4;
    const float p0 = pec[r0], p1 = pec[r1], p2 = pec[r2];
    f4 v3; float p3 = 0.f; int r3 = 0;
    if (t < 16) { v3 = xin[t + 768]; r3 = (t + 768) / NF4; p3 = pec[r3]; }

    // ---- Bt[h][m] = wt[(m-h) mod 56] bf16 (circulant B-operand table).
    //      Independent of other threads' LDS -> covered by the one barrier.
    //      wc is 224B, L1-resident; VALU here overlaps the x-load latency.
    {
        const int h = t >> 2, mb = (t & 3) << 4;     // 16 consecutive m per thread
        const int j0 = (mb - h + 112) % 56;          // in [0,55]
        u32 d[8];
        #pragma unroll
        for (int i = 0; i < 8; ++i) {
            int ja = j0 + 2 * i;     if (ja >= 56) ja -= 56;
            int jb = j0 + 2 * i + 1; if (jb >= 56) jb -= 56;
            d[i] = cvtpk_bf16(wc[ja], wc[jb]);
        }
        char* p = (char*)Bt + 144 * h + 2 * mb;      // 16B aligned
        u32x4 w0 = {d[0], d[1], d[2], d[3]};
        u32x4 w1 = {d[4], d[5], d[6], d[7]};
        *reinterpret_cast<u32x4*>(p)      = w0;
        *reinterpret_cast<u32x4*>(p + 16) = w1;
    }

    // ---- zero the m-pad (m=56..63) for ALL 64 w rows: k>=56 terms exact 0.
    //      (w-pad rows stay garbage: they become D rows w>=56, discarded.)
    {
        const int w = t >> 2, j = t & 3, m = 56 + 2 * j;
        const int blk = (m >> 2) ^ swz(w);
        *reinterpret_cast<float2*>((char*)Xt + 256 * w + 16 * blk + 4 * (m & 3))
            = make_float2(0.f, 0.f);
    }

    // ---- scatter to Xt[w=4*w4+q][m=r] (pe fused, fp32) ----
    #define PUT(F, V, R, P) { \
        const int w4_ = (F) % NF4; \
        const int blkb = (R) >> 2, sub = 4 * ((R) & 3); \
        const float a0 = (V).x + (P), a1 = (V).y + (P); \
        const float a2 = (V).z + (P), a3 = (V).w + (P); \
        { const int w = 4 * w4_ + 0; *reinterpret_cast<float*>((char*)Xt + 256*w + 16*(blkb ^ swz(w)) + sub) = a0; } \
        { const int w = 4 * w4_ + 1; *reinterpret_cast<float*>((char*)Xt + 256*w + 16*(blkb ^ swz(w)) + sub) = a1; } \
        { const int w = 4 * w4_ + 2; *reinterpret_cast<float*>((char*)Xt + 256*w + 16*(blkb ^ swz(w)) + sub) = a2; } \
        { const int w = 4 * w4_ + 3; *reinterpret_cast<float*>((char*)Xt + 256*w + 16*(blkb ^ swz(w)) + sub) = a3; } }
    PUT(t,       v0, r0, p0)
    PUT(t + 256, v1, r1, p1)
    PUT(t + 512, v2, r2, p2)
    if (t < 16) PUT(t + 768, v3, r3, p3)
    #undef PUT
    __syncthreads();

    // ---- MFMA (transposed): wave wv owns D rows w = 16wv..16wv+15, all 64 h.
    //      A-frag: Xt[16wv+l15][8g+32step .. +7] fp32 -> cvt_pk (2 b128/lane/step)
    //      B-frag: Bt[16j+l15][8g+32step .. +7] bf16 (1 b128, shared A across j)
    const int l = t & 63, wv = t >> 6, l15 = l & 15, g = l >> 4;
    const int wA = 16 * wv + l15;
    const int sA = swz(wA);

    const float bz = bias[c];
    f32x4 acc[4];
    #pragma unroll
    for (int j = 0; j < 4; ++j) acc[j] = (f32x4){bz, bz, bz, bz};

    #pragma unroll
    for (int step = 0; step < 2; ++step) {
        const int blk0 = 2 * g + 8 * step;            // m0 = 8g+32step
        const f32x4 lo = *reinterpret_cast<const f32x4*>((char*)Xt + 256 * wA + 16 * (blk0 ^ sA));
        const f32x4 hi = *reinterpret_cast<const f32x4*>((char*)Xt + 256 * wA + 16 * ((blk0 + 1) ^ sA));
        union { u32 d[4]; short8 s8; } au;
        au.d[0] = cvtpk_bf16(lo[0], lo[1]);
        au.d[1] = cvtpk_bf16(lo[2], lo[3]);
        au.d[2] = cvtpk_bf16(hi[0], hi[1]);
        au.d[3] = cvtpk_bf16(hi[2], hi[3]);
        #pragma unroll
        for (int j = 0; j < 4; ++j) {
            const short8 bfr = *reinterpret_cast<const short8*>(
                (char*)Bt + 144 * (16 * j + l15) + 16 * g + 64 * step);
            acc[j] = __builtin_amdgcn_mfma_f32_16x16x32_bf16(au.s8, bfr, acc[j], 0, 0, 0);
        }
    }

    // ---- D[w][h]: col h=16j+l15, rows w=16wv+4g+{0..3} (consecutive!) ----
    //      -> one ds_write_b128 per j into Cb[h][w] (stride 60: 2-way banks/quarter)
    #pragma unroll
    for (int j = 0; j < 4; ++j) {
        const int h = 16 * j + l15;
        if (h < Hh && !(wv == 3 && g >= 2))           // w=16wv+4g+3 <= 55
            *reinterpret_cast<f32x4*>((char*)Cb + 240 * h + 64 * wv + 16 * g) = acc[j];
    }
    __syncthreads();

    // ---- out stores: linear f4 => 1KB contiguous/wave-instr ----
    f4* __restrict__ op = reinterpret_cast<f4*>(out) + (size_t)bc * (PLANE / 4);
    #define GETST(U) { \
        const int rr = (U) / NF4, ww4 = (U) % NF4; \
        op[(U)] = *reinterpret_cast<const f4*>((char*)Cb + 240 * rr + 16 * ww4); }
    GETST(t)
    GETST(t + 256)
    GETST(t + 512)
    if (t < 16) GETST(t + 768)
    #undef GETST
}

extern "C" void kernel_launch(void* const* d_in, const int* in_sizes, int n_in,
                              void* d_out, int out_size, void* d_ws, size_t ws_size,
                              hipStream_t stream) {
    const float* x  = (const float*)d_in[0];
    const float* pe = (const float*)d_in[1];
    const float* w  = (const float*)d_in[2];
    const float* b  = (const float*)d_in[3];
    float* out      = (float*)d_out;

    parc_kernel<<<dim3(32 * Cc), 256, 0, stream>>>(x, pe, w, b, out);
}

// Round 2
// 56.586 us; speedup vs baseline: 1.1265x; 1.1265x over previous
//
#include <hip/hip_runtime.h>

#define Cc 384
#define Hh 56
#define Ww 56
#define PLANE (Hh*Ww)        // 3136 floats
#define NF4 14               // float4s per row

typedef short short8 __attribute__((ext_vector_type(8)));
typedef float f32x4  __attribute__((ext_vector_type(4)));
typedef unsigned int u32;
struct __align__(16) f4 { float x, y, z, w; };

__device__ __forceinline__ u32 cvtpk_bf16(float a, float b) {
    u32 d; asm("v_cvt_pk_bf16_f32 %0, %1, %2" : "=v"(d) : "v"(a), "v"(b));
    return d;   // lo=bf16(a), hi=bf16(b), RNE
}
// 16B-block swizzle within a 128B Xt row (8 blocks): good for BOTH the
// staging scatter (w = 4*w4+q, w4 varies per lane: swz takes 8 distinct
// values per phase) and the b128 frag reads (w = 16ni+l15: swz over 16
// consecutive w covers 0..7 twice -> 2 lanes per 16B block = free 2-way).
__device__ __forceinline__ int swz(int w) { return (w ^ (w >> 2)) & 7; }

// out = A(56x56 circulant) * X(56x56) per plane, padded to 64^3, bf16 MFMA.
// R13: occupancy 38->53->75% made dur WORSE -> not latency-bound.
// R14: both HBM streams fully contiguous (1KB/wave-instr) -> 58.0us.
// R15 FAILED (63.7): transposed decomposition cut DS but its circulant
//   B-table build needed 16 per-lane-divergent global gathers -> VMEM blowup.
// R16 (this round): stay in R14 orientation; Xt stored as bf16.
//   - cvt moves from MFMA phase (32/lane on 4x-redundant reads) to scatter
//     (12.25/lane, once). RNE at write == RNE at read: numerics identical.
//   - B-frag = ONE ds_read_b128 (was 2): phase-2 DS 1510 -> ~1130 cyc/block,
//     DS/gen 9530 -> ~8000 vs HBM 10000: DS no longer co-critical.
//   - LDS 30.2KB -> 21.9KB.
// waves_per_eu(4,4): the only codegen mode without the VGPR-24 pathology.
__global__ __launch_bounds__(256) __attribute__((amdgpu_waves_per_eu(4, 4)))
void parc_kernel(const float* __restrict__ x, const float* __restrict__ pe,
                 const float* __restrict__ wgt, const float* __restrict__ bias,
                 float* __restrict__ out)
{
    __shared__ __align__(16) unsigned short Xt16[64 * 64]; // [w][m] bf16, swizzled 16B blocks (8KB)
    __shared__ __align__(16) float Cb[56 * 60];            // [h][w] stride 60 dwords (13.4KB)
    __shared__ unsigned short wt2[112];                    // wt[k%56] bf16

    const int t  = threadIdx.x;
    const int bc = blockIdx.x;          // plane index b*C + c
    const int c  = bc % Cc;

    const float* __restrict__ wc  = wgt + c * Hh;
    const float* __restrict__ pec = pe  + c * Hh;
    const f4* __restrict__ xin = reinterpret_cast<const f4*>(x) + (size_t)bc * (PLANE / 4);

    // ---- staging loads: linear f4 => 64 lanes x 16B = 1KB contiguous/instr ----
    f4 v0 = xin[t], v1 = xin[t + 256], v2 = xin[t + 512];
    const int r0 = t / NF4, r1 = (t + 256) / NF4, r2 = (t + 512) / NF4;
    const float p0 = pec[r0], p1 = pec[r1], p2 = pec[r2];
    f4 v3; float p3 = 0.f; int r3 = 0;
    if (t < 16) { v3 = xin[t + 768]; r3 = (t + 768) / NF4; p3 = pec[r3]; }

    // ---- weights -> bf16 in LDS (mod-56 duplicated) ----
    if (t < 112) {
        const int k = t >= Hh ? t - Hh : t;
        wt2[t] = (unsigned short)(cvtpk_bf16(wc[k], wc[k]) & 0xffffu);
    }

    // ---- zero the m-pad (m=56..63) for ALL 64 w rows: k>=56 terms exact 0.
    //      (w-pad rows stay garbage: MFMA columns are independent, those
    //       columns are discarded at the C-write.)
    {
        const int w = t >> 2, j = t & 3;                   // m = 56+2j, 57+2j
        const int blk = 7 ^ swz(w);                        // m>>3 == 7
        *reinterpret_cast<u32*>((char*)Xt16 + 128 * w + 16 * blk + 4 * j) = 0u;
    }

    // ---- scatter to Xt16[w=4*w4+q][m=r] (pe fused, bf16 RNE) ----
    #define PUT(F, V, R, P) { \
        const int w4_ = (F) % NF4; \
        const int blkb = (R) >> 3, sub = 2 * ((R) & 7); \
        const unsigned short b0 = (unsigned short)cvtpk_bf16((V).x + (P), 0.f); \
        const unsigned short b1 = (unsigned short)cvtpk_bf16((V).y + (P), 0.f); \
        const unsigned short b2 = (unsigned short)cvtpk_bf16((V).z + (P), 0.f); \
        const unsigned short b3 = (unsigned short)cvtpk_bf16((V).w + (P), 0.f); \
        { const int w = 4 * w4_ + 0; *reinterpret_cast<unsigned short*>((char*)Xt16 + 128*w + 16*(blkb ^ swz(w)) + sub) = b0; } \
        { const int w = 4 * w4_ + 1; *reinterpret_cast<unsigned short*>((char*)Xt16 + 128*w + 16*(blkb ^ swz(w)) + sub) = b1; } \
        { const int w = 4 * w4_ + 2; *reinterpret_cast<unsigned short*>((char*)Xt16 + 128*w + 16*(blkb ^ swz(w)) + sub) = b2; } \
        { const int w = 4 * w4_ + 3; *reinterpret_cast<unsigned short*>((char*)Xt16 + 128*w + 16*(blkb ^ swz(w)) + sub) = b3; } }
    PUT(t,       v0, r0, p0)
    PUT(t + 256, v1, r1, p1)
    PUT(t + 512, v2, r2, p2)
    if (t < 16) PUT(t + 768, v3, r3, p3)
    #undef PUT
    __syncthreads();

    // ---- MFMA: wave wv computes C rows 16wv..16wv+15 ----
    const int l = t & 63, wv = t >> 6, l15 = l & 15, g = l >> 4;

    // A-frags: A[h][m] = wt[(m-h)%56]; lane row h=16wv+l15, k(m)=8g+j+32step
    short8 afr[2];
    #pragma unroll
    for (int step = 0; step < 2; ++step) {
        #pragma unroll
        for (int j = 0; j < 8; ++j) {
            int idx = 32 * step + 8 * g + j - 16 * wv - l15 + 56;
            idx = idx < 0 ? 0 : (idx > 111 ? 111 : idx);   // pad m>=56 hits zeroed X cols
            afr[step][j] = (short)wt2[idx];
        }
    }

    const float bz = bias[c];
    f32x4 acc[4];
    #pragma unroll
    for (int ni = 0; ni < 4; ++ni) acc[ni] = (f32x4){bz, bz, bz, bz};

    #pragma unroll
    for (int step = 0; step < 2; ++step) {
        #pragma unroll
        for (int ni = 0; ni < 4; ++ni) {
            const int w = 16 * ni + l15;              // B col n = l15
            const int blk0 = g + 4 * step;            // m0 = 8g+32step
            const short8 bfr = *reinterpret_cast<const short8*>(
                (char*)Xt16 + 128 * w + 16 * (blk0 ^ swz(w)));
            acc[ni] = __builtin_amdgcn_mfma_f32_16x16x32_bf16(afr[step], bfr, acc[ni], 0, 0, 0);
        }
    }

    // ---- D (col=l15, row=4g+reg) -> Cb[h][w] (stride 60: 2-way banks) ----
    #pragma unroll
    for (int ni = 0; ni < 4; ++ni) {
        const int wcol = 16 * ni + l15;
        #pragma unroll
        for (int r = 0; r < 4; ++r) {
            const int h = 16 * wv + 4 * g + r;
            if (h < Hh && wcol < Ww) Cb[60 * h + wcol] = acc[ni][r];
        }
    }
    __syncthreads();

    // ---- out stores: linear f4 => 1KB contiguous/wave-instr ----
    f4* __restrict__ op = reinterpret_cast<f4*>(out) + (size_t)bc * (PLANE / 4);
    #define GETST(U) { \
        const int rr = (U) / NF4, ww4 = (U) % NF4; \
        op[(U)] = *reinterpret_cast<const f4*>((char*)Cb + 240 * rr + 16 * ww4); }
    GETST(t)
    GETST(t + 256)
    GETST(t + 512)
    if (t < 16) GETST(t + 768)
    #undef GETST
}

extern "C" void kernel_launch(void* const* d_in, const int* in_sizes, int n_in,
                              void* d_out, int out_size, void* d_ws, size_t ws_size,
                              hipStream_t stream) {
    const float* x  = (const float*)d_in[0];
    const float* pe = (const float*)d_in[1];
    const float* w  = (const float*)d_in[2];
    const float* b  = (const float*)d_in[3];
    float* out      = (float*)d_out;

    parc_kernel<<<dim3(32 * Cc), 256, 0, stream>>>(x, pe, w, b, out);
}

// Round 3
// 54.089 us; speedup vs baseline: 1.1785x; 1.0462x over previous
//
#include <hip/hip_runtime.h>

#define Cc 384
#define Hh 56
#define Ww 56
#define PLANE (Hh*Ww)        // 3136 floats
#define NF4 14               // float4s per row
#define NBLK 2048            // persistent-ish grid
#define NPL 6                // planes per block: 2048*6 = 12288

typedef short short8 __attribute__((ext_vector_type(8)));
typedef float f32x4  __attribute__((ext_vector_type(4)));
typedef unsigned int u32;
struct __align__(16) f4 { float x, y, z, w; };

__device__ __forceinline__ u32 cvtpk_bf16(float a, float b) {
    u32 d; asm("v_cvt_pk_bf16_f32 %0, %1, %2" : "=v"(d) : "v"(a), "v"(b));
    return d;   // lo=bf16(a), hi=bf16(b), RNE
}
// 16B-block swizzle within a 128B Xt row (8 blocks): good for BOTH the
// staging scatter (w = 4*w4+q) and the b128 frag reads (w = 16ni+l15).
__device__ __forceinline__ int swz(int w) { return (w ^ (w >> 2)) & 7; }

// out = A(56x56 circulant) * X(56x56) per plane, padded to 64^3, bf16 MFMA.
// R13: occupancy 38->53->75% made dur WORSE -> not latency-bound by waves.
// R14: both HBM streams fully contiguous (1KB/wave-instr) -> 58.0us.
// R15 FAILED (63.7): transposed decomposition needed per-lane wc gathers.
// R16 (56.6): Xt stored bf16 -> B-frag is ONE ds_read_b128; DS off crit path.
// R17 (this round): 86.6% of copy ceiling; remaining gap = per-block
//   load-latency exposure (~380 cyc HBM idle/generation). Persistent-ish
//   blocks (2048 x 6 planes): next plane's loads ISSUED during MFMA phase,
//   consumed in post-store scatter -> 5/6 of plane-loads latency-hidden.
//   Phase internals byte-identical; zero-pad hoisted (scatter never touches
//   pad cells); wt2 double-buffered (448B).
// waves_per_eu(4,4): the only codegen mode without the VGPR-24 pathology.
__global__ __launch_bounds__(256) __attribute__((amdgpu_waves_per_eu(4, 4)))
void parc_kernel(const float* __restrict__ x, const float* __restrict__ pe,
                 const float* __restrict__ wgt, const float* __restrict__ bias,
                 float* __restrict__ out)
{
    __shared__ __align__(16) unsigned short Xt16[64 * 64]; // [w][m] bf16, swizzled 16B blocks (8KB)
    __shared__ __align__(16) float Cb[56 * 60];            // [h][w] stride 60 dwords (13.4KB)
    __shared__ unsigned short wt2[2][112];                 // wt[k%56] bf16, double-buffered

    const int t   = threadIdx.x;
    const int blk = blockIdx.x;

    const int r0 = t / NF4, r1 = (t + 256) / NF4, r2 = (t + 512) / NF4, r3 = (t + 768) / NF4;
    const int kw = t >= Hh ? t - Hh : t;                   // weight dup index (t<112)
    const int l = t & 63, wvi = t >> 6, l15 = l & 15, g = l >> 4;

    // ---- zero the m-pad (m=56..63) ONCE: scatter only writes m<=55, so the
    //      pad cells survive all NPL re-scatters. ----
    {
        const int w = t >> 2, j = t & 3;
        const int blkz = 7 ^ swz(w);                       // m>>3 == 7
        *reinterpret_cast<u32*>((char*)Xt16 + 128 * w + 16 * blkz + 4 * j) = 0u;
    }

    f4 v0, v1, v2, v3 = {};
    float p0 = 0.f, p1 = 0.f, p2 = 0.f, p3 = 0.f, wld = 0.f, bz = 0.f;

    // issue next-plane global loads (registers only; no LDS touch)
    #define ISSUE(BC) { \
        const f4* __restrict__ xin = reinterpret_cast<const f4*>(x) + (size_t)(BC) * (PLANE / 4); \
        const int c_ = (BC) % Cc; \
        const float* __restrict__ pec = pe + c_ * Hh; \
        v0 = xin[t]; v1 = xin[t + 256]; v2 = xin[t + 512]; \
        p0 = pec[r0]; p1 = pec[r1]; p2 = pec[r2]; \
        if (t < 16) { v3 = xin[t + 768]; p3 = pec[r3]; } \
        if (t < 112) wld = wgt[c_ * Hh + kw]; \
        bz = bias[c_]; }

    #define PUT(F, V, R, P) { \
        const int w4_ = (F) % NF4; \
        const int blkb = (R) >> 3, sub = 2 * ((R) & 7); \
        const unsigned short b0 = (unsigned short)cvtpk_bf16((V).x + (P), 0.f); \
        const unsigned short b1 = (unsigned short)cvtpk_bf16((V).y + (P), 0.f); \
        const unsigned short b2 = (unsigned short)cvtpk_bf16((V).z + (P), 0.f); \
        const unsigned short b3 = (unsigned short)cvtpk_bf16((V).w + (P), 0.f); \
        { const int w = 4 * w4_ + 0; *reinterpret_cast<unsigned short*>((char*)Xt16 + 128*w + 16*(blkb ^ swz(w)) + sub) = b0; } \
        { const int w = 4 * w4_ + 1; *reinterpret_cast<unsigned short*>((char*)Xt16 + 128*w + 16*(blkb ^ swz(w)) + sub) = b1; } \
        { const int w = 4 * w4_ + 2; *reinterpret_cast<unsigned short*>((char*)Xt16 + 128*w + 16*(blkb ^ swz(w)) + sub) = b2; } \
        { const int w = 4 * w4_ + 3; *reinterpret_cast<unsigned short*>((char*)Xt16 + 128*w + 16*(blkb ^ swz(w)) + sub) = b3; } }

    #define SCATTER(PAR) { \
        if (t < 112) wt2[PAR][t] = (unsigned short)(cvtpk_bf16(wld, wld) & 0xffffu); \
        PUT(t,       v0, r0, p0) \
        PUT(t + 256, v1, r1, p1) \
        PUT(t + 512, v2, r2, p2) \
        if (t < 16) { PUT(t + 768, v3, r3, p3) } }

    // ---- prologue: plane 0 ----
    ISSUE(blk)
    SCATTER(0)
    float bzc = bz;
    __syncthreads();

    for (int it = 0; it < NPL; ++it) {
        const int par = it & 1;
        const int bc_cur = blk + NBLK * it;

        // A-frags: A[h][m] = wt[(m-h)%56]; lane row h=16wvi+l15, k(m)=8g+j+32step
        short8 afr[2];
        #pragma unroll
        for (int step = 0; step < 2; ++step) {
            #pragma unroll
            for (int j = 0; j < 8; ++j) {
                int idx = 32 * step + 8 * g + j - 16 * wvi - l15 + 56;
                idx = idx < 0 ? 0 : (idx > 111 ? 111 : idx);   // pad m>=56 hits zeroed X cols
                afr[step][j] = (short)wt2[par][idx];
            }
        }

        // prefetch: next plane's loads fly under MFMA + store phases
        if (it + 1 < NPL) { ISSUE(blk + NBLK * (it + 1)) }

        f32x4 acc[4];
        #pragma unroll
        for (int ni = 0; ni < 4; ++ni) acc[ni] = (f32x4){bzc, bzc, bzc, bzc};

        #pragma unroll
        for (int step = 0; step < 2; ++step) {
            #pragma unroll
            for (int ni = 0; ni < 4; ++ni) {
                const int w = 16 * ni + l15;              // B col n = l15
                const int blk0 = g + 4 * step;            // m0 = 8g+32step
                const short8 bfr = *reinterpret_cast<const short8*>(
                    (char*)Xt16 + 128 * w + 16 * (blk0 ^ swz(w)));
                acc[ni] = __builtin_amdgcn_mfma_f32_16x16x32_bf16(afr[step], bfr, acc[ni], 0, 0, 0);
            }
        }

        // ---- D (col=l15, row=4g+reg) -> Cb[h][w] (stride 60: 2-way banks) ----
        #pragma unroll
        for (int ni = 0; ni < 4; ++ni) {
            const int wcol = 16 * ni + l15;
            #pragma unroll
            for (int r = 0; r < 4; ++r) {
                const int h = 16 * wvi + 4 * g + r;
                if (h < Hh && wcol < Ww) Cb[60 * h + wcol] = acc[ni][r];
            }
        }
        __syncthreads();     // B2: Cb ready; all Xt16/wt2 reads of plane `it` done

        // ---- out stores: linear f4 => 1KB contiguous/wave-instr ----
        f4* __restrict__ op = reinterpret_cast<f4*>(out) + (size_t)bc_cur * (PLANE / 4);
        #define GETST(U) { \
            const int rr = (U) / NF4, ww4 = (U) % NF4; \
            op[(U)] = *reinterpret_cast<const f4*>((char*)Cb + 240 * rr + 16 * ww4); }
        GETST(t)
        GETST(t + 256)
        GETST(t + 512)
        if (t < 16) { GETST(t + 768) }
        #undef GETST

        if (it + 1 < NPL) {
            SCATTER(par ^ 1)     // prefetched loads have landed; Xt16 safe after B2
            bzc = bz;
            __syncthreads();     // B1: Xt16/wt2 ready; Cb reads done before next Cb writes
        }
    }
    #undef SCATTER
    #undef PUT
    #undef ISSUE
}

extern "C" void kernel_launch(void* const* d_in, const int* in_sizes, int n_in,
                              void* d_out, int out_size, void* d_ws, size_t ws_size,
                              hipStream_t stream) {
    const float* x  = (const float*)d_in[0];
    const float* pe = (const float*)d_in[1];
    const float* w  = (const float*)d_in[2];
    const float* b  = (const float*)d_in[3];
    float* out      = (float*)d_out;

    parc_kernel<<<dim3(NBLK), 256, 0, stream>>>(x, pe, w, b, out);
}

// Round 4
// 53.928 us; speedup vs baseline: 1.1821x; 1.0030x over previous
//
#include <hip/hip_runtime.h>

#define Cc 384
#define Hh 56
#define Ww 56
#define PLANE (Hh*Ww)        // 3136 floats
#define NF4 14               // float4s per row
#define NBLK 2048            // persistent-ish grid
#define NPL 6                // planes per block: 2048*6 = 12288

typedef short short8 __attribute__((ext_vector_type(8)));
typedef float f32x4  __attribute__((ext_vector_type(4)));
typedef unsigned int u32;
struct __align__(16) f4 { float x, y, z, w; };

__device__ __forceinline__ u32 cvtpk_bf16(float a, float b) {
    u32 d; asm("v_cvt_pk_bf16_f32 %0, %1, %2" : "=v"(d) : "v"(a), "v"(b));
    return d;   // lo=bf16(a), hi=bf16(b), RNE
}
// 16B-block swizzle within a 128B Xt row (8 blocks): good for BOTH the
// staging scatter (w = 4*w4+q) and the b128 frag reads (w = 16ni+l15).
__device__ __forceinline__ int swz(int w) { return (w ^ (w >> 2)) & 7; }

// LDS-only barrier: drains lgkmcnt (all cross-thread data in this kernel
// flows through LDS) but leaves vmcnt IN FLIGHT -> the prefetched x-loads
// are not force-drained at the barrier (__syncthreads emits vmcnt(0)).
// All LDS traffic here is compiler-generated, so ds dependency tracking
// and vmcnt insertion before v0..v3 use still happen normally.
#define BAR() asm volatile("s_waitcnt lgkmcnt(0)\n\ts_barrier" ::: "memory")

// out = A(56x56 circulant) * X(56x56) per plane, padded to 64^3, bf16 MFMA.
// R13: occupancy 38->53->75% made dur WORSE -> not latency-bound by waves.
// R14: both HBM streams fully contiguous (1KB/wave-instr) -> 58.0us.
// R15 FAILED (63.7): transposed decomposition needed per-lane wc gathers.
// R16 (56.6): Xt stored bf16 -> B-frag is ONE ds_read_b128; DS off crit path.
// R17 (54.1): persistent blocks (2048 x 6 planes), next-plane loads issued
//   under MFMA phase -> 5/6 plane-loads latency-hidden (partially).
// R18 (this round): __syncthreads drains vmcnt(0) at B2, truncating the
//   prefetch window to the MFMA phase only. Replace both barriers with
//   lgkmcnt-only s_barrier -> prefetch stays in flight across B2 until
//   its SCATTER use (T4: never drain vmcnt in the main loop).
// waves_per_eu(4,4): the only codegen mode without the VGPR-24 pathology.
__global__ __launch_bounds__(256) __attribute__((amdgpu_waves_per_eu(4, 4)))
void parc_kernel(const float* __restrict__ x, const float* __restrict__ pe,
                 const float* __restrict__ wgt, const float* __restrict__ bias,
                 float* __restrict__ out)
{
    __shared__ __align__(16) unsigned short Xt16[64 * 64]; // [w][m] bf16, swizzled 16B blocks (8KB)
    __shared__ __align__(16) float Cb[56 * 60];            // [h][w] stride 60 dwords (13.4KB)
    __shared__ unsigned short wt2[2][112];                 // wt[k%56] bf16, double-buffered

    const int t   = threadIdx.x;
    const int blk = blockIdx.x;

    const int r0 = t / NF4, r1 = (t + 256) / NF4, r2 = (t + 512) / NF4, r3 = (t + 768) / NF4;
    const int kw = t >= Hh ? t - Hh : t;                   // weight dup index (t<112)
    const int l = t & 63, wvi = t >> 6, l15 = l & 15, g = l >> 4;

    // ---- zero the m-pad (m=56..63) ONCE: scatter only writes m<=55, so the
    //      pad cells survive all NPL re-scatters. ----
    {
        const int w = t >> 2, j = t & 3;
        const int blkz = 7 ^ swz(w);                       // m>>3 == 7
        *reinterpret_cast<u32*>((char*)Xt16 + 128 * w + 16 * blkz + 4 * j) = 0u;
    }

    f4 v0, v1, v2, v3 = {};
    float p0 = 0.f, p1 = 0.f, p2 = 0.f, p3 = 0.f, wld = 0.f, bz = 0.f;

    // issue next-plane global loads (registers only; no LDS touch)
    #define ISSUE(BC) { \
        const f4* __restrict__ xin = reinterpret_cast<const f4*>(x) + (size_t)(BC) * (PLANE / 4); \
        const int c_ = (BC) % Cc; \
        const float* __restrict__ pec = pe + c_ * Hh; \
        v0 = xin[t]; v1 = xin[t + 256]; v2 = xin[t + 512]; \
        p0 = pec[r0]; p1 = pec[r1]; p2 = pec[r2]; \
        if (t < 16) { v3 = xin[t + 768]; p3 = pec[r3]; } \
        if (t < 112) wld = wgt[c_ * Hh + kw]; \
        bz = bias[c_]; }

    #define PUT(F, V, R, P) { \
        const int w4_ = (F) % NF4; \
        const int blkb = (R) >> 3, sub = 2 * ((R) & 7); \
        const unsigned short b0 = (unsigned short)cvtpk_bf16((V).x + (P), 0.f); \
        const unsigned short b1 = (unsigned short)cvtpk_bf16((V).y + (P), 0.f); \
        const unsigned short b2 = (unsigned short)cvtpk_bf16((V).z + (P), 0.f); \
        const unsigned short b3 = (unsigned short)cvtpk_bf16((V).w + (P), 0.f); \
        { const int w = 4 * w4_ + 0; *reinterpret_cast<unsigned short*>((char*)Xt16 + 128*w + 16*(blkb ^ swz(w)) + sub) = b0; } \
        { const int w = 4 * w4_ + 1; *reinterpret_cast<unsigned short*>((char*)Xt16 + 128*w + 16*(blkb ^ swz(w)) + sub) = b1; } \
        { const int w = 4 * w4_ + 2; *reinterpret_cast<unsigned short*>((char*)Xt16 + 128*w + 16*(blkb ^ swz(w)) + sub) = b2; } \
        { const int w = 4 * w4_ + 3; *reinterpret_cast<unsigned short*>((char*)Xt16 + 128*w + 16*(blkb ^ swz(w)) + sub) = b3; } }

    #define SCATTER(PAR) { \
        if (t < 112) wt2[PAR][t] = (unsigned short)(cvtpk_bf16(wld, wld) & 0xffffu); \
        PUT(t,       v0, r0, p0) \
        PUT(t + 256, v1, r1, p1) \
        PUT(t + 512, v2, r2, p2) \
        if (t < 16) { PUT(t + 768, v3, r3, p3) } }

    // ---- prologue: plane 0 ----
    ISSUE(blk)
    SCATTER(0)
    float bzc = bz;
    BAR();

    for (int it = 0; it < NPL; ++it) {
        const int par = it & 1;
        const int bc_cur = blk + NBLK * it;

        // A-frags: A[h][m] = wt[(m-h)%56]; lane row h=16wvi+l15, k(m)=8g+j+32step
        short8 afr[2];
        #pragma unroll
        for (int step = 0; step < 2; ++step) {
            #pragma unroll
            for (int j = 0; j < 8; ++j) {
                int idx = 32 * step + 8 * g + j - 16 * wvi - l15 + 56;
                idx = idx < 0 ? 0 : (idx > 111 ? 111 : idx);   // pad m>=56 hits zeroed X cols
                afr[step][j] = (short)wt2[par][idx];
            }
        }

        // prefetch: next plane's loads fly under MFMA + store phases
        // (and now ACROSS B2, since BAR() leaves vmcnt alone)
        if (it + 1 < NPL) { ISSUE(blk + NBLK * (it + 1)) }

        f32x4 acc[4];
        #pragma unroll
        for (int ni = 0; ni < 4; ++ni) acc[ni] = (f32x4){bzc, bzc, bzc, bzc};

        #pragma unroll
        for (int step = 0; step < 2; ++step) {
            #pragma unroll
            for (int ni = 0; ni < 4; ++ni) {
                const int w = 16 * ni + l15;              // B col n = l15
                const int blk0 = g + 4 * step;            // m0 = 8g+32step
                const short8 bfr = *reinterpret_cast<const short8*>(
                    (char*)Xt16 + 128 * w + 16 * (blk0 ^ swz(w)));
                acc[ni] = __builtin_amdgcn_mfma_f32_16x16x32_bf16(afr[step], bfr, acc[ni], 0, 0, 0);
            }
        }

        // ---- D (col=l15, row=4g+reg) -> Cb[h][w] (stride 60: 2-way banks) ----
        #pragma unroll
        for (int ni = 0; ni < 4; ++ni) {
            const int wcol = 16 * ni + l15;
            #pragma unroll
            for (int r = 0; r < 4; ++r) {
                const int h = 16 * wvi + 4 * g + r;
                if (h < Hh && wcol < Ww) Cb[60 * h + wcol] = acc[ni][r];
            }
        }
        BAR();               // B2: Cb visible; plane-it Xt16/wt2 reads retired

        // ---- out stores: linear f4 => 1KB contiguous/wave-instr ----
        f4* __restrict__ op = reinterpret_cast<f4*>(out) + (size_t)bc_cur * (PLANE / 4);
        #define GETST(U) { \
            const int rr = (U) / NF4, ww4 = (U) % NF4; \
            op[(U)] = *reinterpret_cast<const f4*>((char*)Cb + 240 * rr + 16 * ww4); }
        GETST(t)
        GETST(t + 256)
        GETST(t + 512)
        if (t < 16) { GETST(t + 768) }
        #undef GETST

        if (it + 1 < NPL) {
            SCATTER(par ^ 1)     // first v0 use: compiler inserts the vmcnt wait here
            bzc = bz;
            BAR();               // B1: Xt16/wt2 visible; Cb reads retired before next writes
        }
    }
    #undef SCATTER
    #undef PUT
    #undef ISSUE
}

extern "C" void kernel_launch(void* const* d_in, const int* in_sizes, int n_in,
                              void* d_out, int out_size, void* d_ws, size_t ws_size,
                              hipStream_t stream) {
    const float* x  = (const float*)d_in[0];
    const float* pe = (const float*)d_in[1];
    const float* w  = (const float*)d_in[2];
    const float* b  = (const float*)d_in[3];
    float* out      = (float*)d_out;

    parc_kernel<<<dim3(NBLK), 256, 0, stream>>>(x, pe, w, b, out);
}

// Round 6
// 53.702 us; speedup vs baseline: 1.1870x; 1.0042x over previous
//
#include <hip/hip_runtime.h>

#define Cc 384
#define Hh 56
#define Ww 56
#define PLANE (Hh*Ww)        // 3136 floats
#define NF4 14               // float4s per row
#define NBLK 2048            // persistent-ish grid
#define NPL 6                // planes per block: 2048*6 = 12288

typedef short short8 __attribute__((ext_vector_type(8)));
typedef float f32x4  __attribute__((ext_vector_type(4)));
typedef unsigned int u32;
typedef u32 u32x2 __attribute__((ext_vector_type(2)));
struct __align__(16) f4 { float x, y, z, w; };

__device__ __forceinline__ u32 cvtpk_bf16(float a, float b) {
    u32 d; asm("v_cvt_pk_bf16_f32 %0, %1, %2" : "=v"(d) : "v"(a), "v"(b));
    return d;   // lo=bf16(a), hi=bf16(b), RNE
}
// 16B-block swizzle within a 128B Xt row (8 blocks): good for the staging
// scatter and the b128 frag reads (w = 16ni+l15).
__device__ __forceinline__ int swz(int w) { return (w ^ (w >> 2)) & 7; }

// out = A(56x56 circulant) * X(56x56) per plane, padded to 64^3, bf16 MFMA.
// R14: both HBM streams contiguous -> 58.0us.
// R15 FAILED (63.7): transposed MFMA needed per-lane wc gathers -> VMEM blowup.
// R16 (56.6): Xt stored bf16 -> B-frag is ONE ds_read_b128.
// R17 (54.1): persistent blocks (2048 x 6), next-plane loads under MFMA.
// R18 (53.9, neutral): lgkmcnt-only asm barrier -- neutral perf.
// R19 FAILED post-timing (race): quad staging passed the pre-timing check
//   (mapping correct) but diverged under graph replay. Prime suspect: the
//   hand-rolled asm barrier (compiler can't model an s_barrier hidden in
//   inline asm; it was perf-neutral anyway). Secondary: garbage bf16 in
//   never-written Xt16 w-rows 56..63 fed to MFMA.
// R20 (this round): KEEP quad staging (the DS win: scatter 196 ds_write_b16
//   -> 16 ds_write_b64 wave-instrs/block; DS/plane ~2300 -> ~1500 cyc,
//   under the ~1840-cyc HBM line), REVERT to __syncthreads() (proven R17),
//   and zero w-pad rows 56..63 once (free insurance).
// waves_per_eu(4,4): the only codegen mode without the VGPR-24 pathology.
__global__ __launch_bounds__(256) __attribute__((amdgpu_waves_per_eu(4, 4)))
void parc_kernel(const float* __restrict__ x, const float* __restrict__ pe,
                 const float* __restrict__ wgt, const float* __restrict__ bias,
                 float* __restrict__ out)
{
    __shared__ __align__(16) unsigned short Xt16[64 * 64]; // [w][m] bf16, swizzled 16B blocks (8KB)
    __shared__ __align__(16) float Cb[56 * 60];            // [h][w] stride 60 dwords (13.4KB)
    __shared__ unsigned short wt2[2][112];                 // wt[k%56] bf16, double-buffered

    const int t   = threadIdx.x;
    const int blk = blockIdx.x;

    // quad staging geometry (t<196): hg in 0..13, w4q in 0..13
    const int hg = t / NF4, w4q = t % NF4;
    const int Fq = 56 * hg + w4q;                          // f4 index of row 4hg, this w4
    const int kw = t >= Hh ? t - Hh : t;                   // weight dup index (t<112)
    const int l = t & 63, wvi = t >> 6, l15 = l & 15, g = l >> 4;

    // ---- one-time zeroing (scatter never touches these cells):
    //      (a) m-pad (logical m-block 7) of ALL rows: k>=56 terms exact 0.
    //      (b) w-pad rows 56..63 entirely: no garbage/NaN bf16 into MFMA.
    {
        const int w = t >> 2, j = t & 3;
        const int blkz = 7 ^ swz(w);                       // logical m-block 7
        *reinterpret_cast<u32*>((char*)Xt16 + 128 * w + 16 * blkz + 4 * j) = 0u;
        const int wz = 56 + (t >> 5);                      // rows 56..63, full 128B
        *reinterpret_cast<u32*>((char*)Xt16 + 128 * wz + 4 * (t & 31)) = 0u;
    }

    f32x4 v0 = {}, v1 = {}, v2 = {}, v3 = {};
    float p0 = 0.f, p1 = 0.f, p2 = 0.f, p3 = 0.f, wld = 0.f, bz = 0.f;

    // issue next-plane global loads (registers only; no LDS touch)
    #define ISSUE(BC) { \
        const f32x4* __restrict__ xin = reinterpret_cast<const f32x4*>(x) + (size_t)(BC) * (PLANE / 4); \
        const int c_ = (BC) % Cc; \
        const float* __restrict__ pec = pe + c_ * Hh; \
        if (t < 196) { \
            v0 = xin[Fq]; v1 = xin[Fq + 14]; v2 = xin[Fq + 28]; v3 = xin[Fq + 42]; \
            p0 = pec[4 * hg]; p1 = pec[4 * hg + 1]; p2 = pec[4 * hg + 2]; p3 = pec[4 * hg + 3]; \
        } \
        if (t < 112) wld = wgt[c_ * Hh + kw]; \
        bz = bias[c_]; }

    // scatter: 4 ds_write_b64 per thread (4 consecutive m per w-row),
    // conflict-free minimum (4 dwords/bank-group; 14 distinct (blk,sub8) pairs)
    #define SCATTER(PAR) { \
        if (t < 112) wt2[PAR][t] = (unsigned short)(cvtpk_bf16(wld, wld) & 0xffffu); \
        if (t < 196) { \
            const int blkb = hg >> 1, sub8 = 8 * (hg & 1); \
            _Pragma("unroll") \
            for (int q = 0; q < 4; ++q) { \
                const int w = 4 * w4q + q; \
                u32x2 d; \
                d[0] = cvtpk_bf16(v0[q] + p0, v1[q] + p1); \
                d[1] = cvtpk_bf16(v2[q] + p2, v3[q] + p3); \
                *reinterpret_cast<u32x2*>((char*)Xt16 + 128 * w + 16 * (blkb ^ swz(w)) + sub8) = d; \
            } \
        } }

    // ---- prologue: plane 0 ----
    ISSUE(blk)
    SCATTER(0)
    float bzc = bz;
    __syncthreads();

    for (int it = 0; it < NPL; ++it) {
        const int par = it & 1;
        const int bc_cur = blk + NBLK * it;

        // A-frags: A[h][m] = wt[(m-h)%56]; lane row h=16wvi+l15, k(m)=8g+j+32step
        short8 afr[2];
        #pragma unroll
        for (int step = 0; step < 2; ++step) {
            #pragma unroll
            for (int j = 0; j < 8; ++j) {
                int idx = 32 * step + 8 * g + j - 16 * wvi - l15 + 56;
                idx = idx < 0 ? 0 : (idx > 111 ? 111 : idx);   // pad m>=56 hits zeroed X cols
                afr[step][j] = (short)wt2[par][idx];
            }
        }

        // prefetch: next plane's loads fly under MFMA + store phases
        if (it + 1 < NPL) { ISSUE(blk + NBLK * (it + 1)) }

        f32x4 acc[4];
        #pragma unroll
        for (int ni = 0; ni < 4; ++ni) acc[ni] = (f32x4){bzc, bzc, bzc, bzc};

        #pragma unroll
        for (int step = 0; step < 2; ++step) {
            #pragma unroll
            for (int ni = 0; ni < 4; ++ni) {
                const int w = 16 * ni + l15;              // B col n = l15
                const int blk0 = g + 4 * step;            // m0 = 8g+32step
                const short8 bfr = *reinterpret_cast<const short8*>(
                    (char*)Xt16 + 128 * w + 16 * (blk0 ^ swz(w)));
                acc[ni] = __builtin_amdgcn_mfma_f32_16x16x32_bf16(afr[step], bfr, acc[ni], 0, 0, 0);
            }
        }

        // ---- D (col=l15, row=4g+reg) -> Cb[h][w] (stride 60: 2-way banks) ----
        #pragma unroll
        for (int ni = 0; ni < 4; ++ni) {
            const int wcol = 16 * ni + l15;
            #pragma unroll
            for (int r = 0; r < 4; ++r) {
                const int h = 16 * wvi + 4 * g + r;
                if (h < Hh && wcol < Ww) Cb[60 * h + wcol] = acc[ni][r];
            }
        }
        __syncthreads();     // B2: Cb visible; plane-it Xt16/wt2 reads retired

        // ---- out stores: linear f4 => 1KB contiguous/wave-instr ----
        f4* __restrict__ op = reinterpret_cast<f4*>(out) + (size_t)bc_cur * (PLANE / 4);
        #define GETST(U) { \
            const int rr = (U) / NF4, ww4 = (U) % NF4; \
            op[(U)] = *reinterpret_cast<const f4*>((char*)Cb + 240 * rr + 16 * ww4); }
        GETST(t)
        GETST(t + 256)
        GETST(t + 512)
        if (t < 16) { GETST(t + 768) }
        #undef GETST

        if (it + 1 < NPL) {
            SCATTER(par ^ 1)     // prefetched loads land here (compiler vmcnt wait)
            bzc = bz;
            __syncthreads();     // B1: Xt16/wt2 visible; Cb reads retired before next writes
        }
    }
    #undef SCATTER
    #undef ISSUE
}

extern "C" void kernel_launch(void* const* d_in, const int* in_sizes, int n_in,
                              void* d_out, int out_size, void* d_ws, size_t ws_size,
                              hipStream_t stream) {
    const float* x  = (const float*)d_in[0];
    const float* pe = (const float*)d_in[1];
    const float* w  = (const float*)d_in[2];
    const float* b  = (const float*)d_in[3];
    float* out      = (float*)d_out;

    parc_kernel<<<dim3(NBLK), 256, 0, stream>>>(x, pe, w, b, out);
}